// Round 2
// baseline (779.953 us; speedup 1.0000x reference)
//
#include <hip/hip_runtime.h>
#include <hip/hip_cooperative_groups.h>

namespace cg = cooperative_groups;

// Input: x (32, 256, 64, 64) fp32. STRIDE=2, P=2. H,W even -> no padding.
//
// Fused cooperative kernel: phase 1 computes per-(batch, block) partial sums
// of squares of the 4 polyphase components (lane-contiguous f4 stream, 1 KiB
// dense per wave-load; lane row-parity (h&1) is invariant under the +16384-f4
// grid stride, so each lane keeps only two sums and a parity-split shuffle
// tree sorts them into the 4 components). __threadfence + grid.sync() makes
// the 32 KB ws array visible device-wide (cross-XCD safe), then phase 2 does
// a redundant per-block argmax (strict > == jnp.argmax first-max tie rule)
// and gathers the winning component with dense lane-contiguous f4 loads
// (L3-hot) and 512 B/wave NT f2 stores.
//
// Grid (64,32) = 2048 blocks @ lb(256,8) -> exactly 8 blocks/CU on 256 CUs,
// fully co-resident, so the cooperative grid sync is legal. Fallback to the
// verified two-kernel path if the cooperative launch is rejected.

#define B 32
#define C 256
#define H 64
#define W 64
#define H2 32
#define W2 32
#define NBLK 64                              // blocks per batch (both phases)
#define IN_F4_PER_BATCH (C * H * W / 4)      // 262144
#define T1 (NBLK * 256)                      // 16384 phase-1 threads per batch
#define ITER1 (IN_F4_PER_BATCH / T1)         // 16
#define SEL_F2_PER_BATCH (C * H2 * W2 / 2)   // 131072 out float2 per batch
#define F2_PER_BLK (SEL_F2_PER_BATCH / NBLK) // 2048
#define ITER2 (F2_PER_BLK / 256)             // 8
// fallback pass-2 geometry
#define GBLK 128
#define T2 (GBLK * 256)
#define ITER2F (SEL_F2_PER_BATCH / T2)       // 4

typedef float floatx2 __attribute__((ext_vector_type(2)));

__device__ __forceinline__ void partials_phase(const float4* __restrict__ xb,
                                               float* __restrict__ ws,
                                               int b, int bx) {
    const int q0 = bx * 256 + threadIdx.x;   // f4 index, lane-contiguous
    float sA = 0.f, sB = 0.f;                // w-even / w-odd sums
#pragma unroll 8
    for (int it = 0; it < ITER1; ++it) {
        float4 v = xb[q0 + it * T1];         // (q>>4)&1 invariant per lane
        sA += v.x * v.x + v.z * v.z;
        sB += v.y * v.y + v.w * v.w;
    }
    // lane row-parity: lanes 0-15,32-47 -> h even; 16-31,48-63 -> h odd
    sA += __shfl_down(sA, 32);  sB += __shfl_down(sB, 32);
#pragma unroll
    for (int off = 8; off; off >>= 1) {
        sA += __shfl_down(sA, off);  sB += __shfl_down(sB, off);
    }
    // lane 0 holds (comp0, comp1); lane 16 holds (comp2, comp3)
    __shared__ float sm[4][4];   // [wave][comp]
    const int lane = threadIdx.x & 63;
    const int wave = threadIdx.x >> 6;
    if (lane == 0)  { sm[wave][0] = sA; sm[wave][1] = sB; }
    if (lane == 16) { sm[wave][2] = sA; sm[wave][3] = sB; }
    __syncthreads();
    if (threadIdx.x < 4) {   // thread k writes comp k's partial
        const int k = threadIdx.x;
        float t = sm[0][k] + sm[1][k] + sm[2][k] + sm[3][k];
        ws[(b * 4 + k) * NBLK + bx] = t;     // contiguous per (b,comp)
    }
}

__device__ __forceinline__ int argmax_phase(const float* __restrict__ ws, int b) {
    const int lane = threadIdx.x & 63;
    const int wave = threadIdx.x >> 6;   // 0..3 == component
    float p = ws[(b * 4 + wave) * NBLK + lane];
    for (int off = 32; off; off >>= 1) p += __shfl_down(p, off);
    __shared__ float s4[4];
    if (lane == 0) s4[wave] = p;
    __syncthreads();
    const float v0 = s4[0], v1 = s4[1], v2 = s4[2], v3 = s4[3];
    float best = v0;
    int k = 0;
    if (v1 > best) { best = v1; k = 1; }
    if (v2 > best) { best = v2; k = 2; }
    if (v3 > best) { k = 3; }
    return k;
}

__device__ __forceinline__ void gather_m(const float4* __restrict__ xb,
                                         floatx2* __restrict__ ob,
                                         int m, int di, int dj) {
    const int ch  = m >> 9;          // 512 out f2 per channel
    const int r   = (m >> 4) & 31;   // output row
    const int col = m & 15;          // f4 column within input row
    // lanes contiguous -> dense 1 KiB per load insn (L3-hot)
    float4 v = xb[(ch * 64 + 2 * r + di) * 16 + col];
    floatx2 o;
    if (dj == 0) { o.x = v.x; o.y = v.z; }   // w even
    else         { o.x = v.y; o.y = v.w; }   // w odd
    __builtin_nontemporal_store(o, ob + m);  // write-once -> NT
}

__global__ __launch_bounds__(256, 8) void aps_fused(const float4* __restrict__ x,
                                                    float* __restrict__ ws,
                                                    floatx2* __restrict__ out) {
    const int b  = blockIdx.y;
    const int bx = blockIdx.x;
    const float4* xb = x + (size_t)b * IN_F4_PER_BATCH;

    partials_phase(xb, ws, b, bx);

    __threadfence();           // release partials device-wide (cross-XCD)
    cg::this_grid().sync();    // all 2048 blocks' partials complete
    __threadfence();           // acquire before reading other XCDs' partials

    const int k  = argmax_phase(ws, b);
    const int di = k >> 1;     // h offset of winning component
    const int dj = k & 1;      // w offset

    floatx2* ob = out + (size_t)b * SEL_F2_PER_BATCH;
    const int m0 = bx * F2_PER_BLK + threadIdx.x;
#pragma unroll
    for (int it = 0; it < ITER2; ++it)
        gather_m(xb, ob, m0 + it * 256, di, dj);
}

// ---------------- fallback two-kernel path (verified round-1 code) ----------
__global__ __launch_bounds__(256, 8) void aps_partials(const float4* __restrict__ x,
                                                       float* __restrict__ ws) {
    const int b = blockIdx.y;
    partials_phase(x + (size_t)b * IN_F4_PER_BATCH, ws, b, blockIdx.x);
}

__global__ __launch_bounds__(256, 8) void aps_gather(const float4* __restrict__ x,
                                                     const float* __restrict__ ws,
                                                     floatx2* __restrict__ out) {
    const int b  = blockIdx.y;
    const int k  = argmax_phase(ws, b);
    const int di = k >> 1, dj = k & 1;
    const float4* xb = x + (size_t)b * IN_F4_PER_BATCH;
    floatx2* ob = out + (size_t)b * SEL_F2_PER_BATCH;
    const int m0 = blockIdx.x * 256 + threadIdx.x;
#pragma unroll
    for (int it = 0; it < ITER2F; ++it)
        gather_m(xb, ob, m0 + it * T2, di, dj);
}

extern "C" void kernel_launch(void* const* d_in, const int* in_sizes, int n_in,
                              void* d_out, int out_size, void* d_ws, size_t ws_size,
                              hipStream_t stream) {
    const float4* x = (const float4*)d_in[0];
    float* ws = (float*)d_ws;             // B*4*NBLK = 8192 floats of partials
    floatx2* out = (floatx2*)d_out;

    void* args[] = {(void*)&x, (void*)&ws, (void*)&out};
    hipError_t e = hipLaunchCooperativeKernel((const void*)aps_fused,
                                              dim3(NBLK, B), dim3(256),
                                              args, 0, stream);
    if (e != hipSuccess) {   // cooperative path rejected -> verified 2-kernel path
        aps_partials<<<dim3(NBLK, B), 256, 0, stream>>>(x, ws);
        aps_gather<<<dim3(GBLK, B), 256, 0, stream>>>(x, ws, out);
    }
}

// Round 3
// 390.361 us; speedup vs baseline: 1.9980x; 1.9980x over previous
//
#include <hip/hip_runtime.h>

// Input: x (32, 256, 64, 64) fp32. STRIDE=2, P=2. H,W even -> no padding.
//
// Single fused kernel with a hand-rolled per-batch barrier (NOT cg::grid.sync,
// which measured ~580us of contention in round 2):
//   phase 1: block bx of batch b streams channels [4bx, 4bx+4) (64 KiB
//     contiguous, 1 KiB dense per wave-load). Lane row-parity (tid>>4)&1 is
//     invariant across iterations, so each lane keeps two sums (w-even/w-odd)
//     and the parity-split shuffle tree sorts them into the 4 polyphase
//     components. Partials published via relaxed agent-scope atomic stores.
//   barrier: per-batch counter (32 separate lines, 64 arrivals each). Only
//     thread 0 polls, RELAXED agent loads (no invalidate storm) + s_sleep
//     backoff; one RELEASE fetch_add publishes. Bounded spin guard -> a
//     residency surprise fails loudly instead of hanging.
//   phase 2: redundant deterministic argmax (strict > == jnp.argmax tie rule)
//     over the 64 partials (relaxed agent atomic loads, cache-bypass -> no
//     staleness), then gather of the winning component from the SAME 64 KiB
//     this block fetched in phase 1 (partial L2 hit), 512 B/wave NT f2 stores.
//
// Grid (64,32) = 2048 blocks @ lb(256,8), ~20 VGPR -> exactly 8 blocks/CU on
// 256 CUs, fully co-resident (geometry validated by round-2's cooperative
// launch). Counters zeroed by a 128 B hipMemsetAsync (graph-capturable).

#define B 32
#define C 256
#define H 64
#define W 64
#define NBLK 64                               // blocks per batch
#define IN_F4_PER_BATCH (C * H * W / 4)       // 262144
#define F4_PER_BLK (IN_F4_PER_BATCH / NBLK)   // 4096 (= 4 channels = 64 KiB)
#define ITER1 (F4_PER_BLK / 256)              // 16
#define SEL_F2_PER_BATCH (C * 32 * 32 / 2)    // 131072 out float2 per batch
#define F2_PER_BLK (SEL_F2_PER_BATCH / NBLK)  // 2048
#define ITER2 (F2_PER_BLK / 256)              // 8
#define SPIN_GUARD (1 << 19)                  // ~0.1 s worst case, then fail loud

typedef float floatx2 __attribute__((ext_vector_type(2)));

__global__ __launch_bounds__(256, 8) void aps_fused(const float4* __restrict__ x,
                                                    unsigned* __restrict__ cnt,
                                                    float* __restrict__ part,
                                                    floatx2* __restrict__ out) {
    const int b  = blockIdx.y;
    const int bx = blockIdx.x;
    const float4* xb = x + (size_t)b * IN_F4_PER_BATCH;
    const int lane = threadIdx.x & 63;
    const int wave = threadIdx.x >> 6;

    // ---- phase 1: partials over this block's 4 contiguous channels ----
    const int q0 = bx * F4_PER_BLK + threadIdx.x;
    float sA = 0.f, sB = 0.f;                 // w-even / w-odd sums
#pragma unroll 8
    for (int it = 0; it < ITER1; ++it) {
        float4 v = xb[q0 + it * 256];         // row parity (tid>>4)&1 invariant
        sA += v.x * v.x + v.z * v.z;
        sB += v.y * v.y + v.w * v.w;
    }
    // lanes 0-15,32-47 -> h even; 16-31,48-63 -> h odd
    sA += __shfl_down(sA, 32);  sB += __shfl_down(sB, 32);
#pragma unroll
    for (int off = 8; off; off >>= 1) {
        sA += __shfl_down(sA, off);  sB += __shfl_down(sB, off);
    }
    __shared__ float sm[4][4];   // [wave][comp]
    if (lane == 0)  { sm[wave][0] = sA; sm[wave][1] = sB; }
    if (lane == 16) { sm[wave][2] = sA; sm[wave][3] = sB; }
    __syncthreads();
    if (threadIdx.x < 4) {       // thread k publishes comp k's partial
        const int k = threadIdx.x;
        float t = sm[0][k] + sm[1][k] + sm[2][k] + sm[3][k];
        __hip_atomic_store(&part[(b * 4 + k) * NBLK + bx], t,
                           __ATOMIC_RELAXED, __HIP_MEMORY_SCOPE_AGENT);
    }
    __syncthreads();             // partial stores complete before release-add

    // ---- per-batch barrier: 64 arrivals on cnt[b] ----
    if (threadIdx.x == 0) {
        __hip_atomic_fetch_add(&cnt[b], 1u,
                               __ATOMIC_RELEASE, __HIP_MEMORY_SCOPE_AGENT);
        int guard = 0;
        while (__hip_atomic_load(&cnt[b], __ATOMIC_RELAXED,
                                 __HIP_MEMORY_SCOPE_AGENT) < NBLK &&
               guard < SPIN_GUARD) {
            __builtin_amdgcn_s_sleep(8);     // ~512 cyc backoff per poll
            ++guard;
        }
    }
    __syncthreads();             // fence for the whole block

    // ---- deterministic redundant argmax (same reduce order every block) ----
    float p = __hip_atomic_load(&part[(b * 4 + wave) * NBLK + lane],
                                __ATOMIC_RELAXED, __HIP_MEMORY_SCOPE_AGENT);
    for (int off = 32; off; off >>= 1) p += __shfl_down(p, off);
    __shared__ float s4[4];
    if (lane == 0) s4[wave] = p;
    __syncthreads();
    const float v0 = s4[0], v1 = s4[1], v2 = s4[2], v3 = s4[3];
    float best = v0;
    int k = 0;
    if (v1 > best) { best = v1; k = 1; }
    if (v2 > best) { best = v2; k = 2; }
    if (v3 > best) { k = 3; }
    const int di = k >> 1;       // h offset of winning component
    const int dj = k & 1;        // w offset

    // ---- gather from this block's own 4 channels (L2-warm) ----
    floatx2* ob = out + (size_t)b * SEL_F2_PER_BATCH;
    const int m0 = bx * F2_PER_BLK + threadIdx.x;
#pragma unroll
    for (int it = 0; it < ITER2; ++it) {
        const int m   = m0 + it * 256;
        const int ch  = m >> 9;          // 512 out f2 per channel
        const int r   = (m >> 4) & 31;   // output row
        const int col = m & 15;          // f4 column within input row
        float4 v = xb[(ch * 64 + 2 * r + di) * 16 + col];
        floatx2 o;
        if (dj == 0) { o.x = v.x; o.y = v.z; }   // w even
        else         { o.x = v.y; o.y = v.w; }   // w odd
        __builtin_nontemporal_store(o, ob + m);  // write-once -> NT
    }
}

extern "C" void kernel_launch(void* const* d_in, const int* in_sizes, int n_in,
                              void* d_out, int out_size, void* d_ws, size_t ws_size,
                              hipStream_t stream) {
    const float4* x = (const float4*)d_in[0];
    unsigned* cnt = (unsigned*)d_ws;          // 32 per-batch counters (128 B)
    float* part = (float*)d_ws + 64;          // 32*4*64 partials (32 KB), 256 B offset
    floatx2* out = (floatx2*)d_out;

    hipMemsetAsync(d_ws, 0, 128, stream);     // zero counters (ws is poisoned)
    aps_fused<<<dim3(NBLK, B), 256, 0, stream>>>(x, cnt, part, out);
}

// Round 4
// 387.148 us; speedup vs baseline: 2.0146x; 1.0083x over previous
//
#include <hip/hip_runtime.h>

// Input: x (32, 256, 64, 64) fp32. STRIDE=2, P=2. H,W even -> no padding.
//
// Single fused kernel with a hand-rolled per-batch barrier.
// Round-2 lesson: cg::grid.sync = ~580us (acquire-INVALIDATE per poll storm).
// Round-3 lesson: AGENT-scope relaxed polling loads are served from the
//   per-XCD L2 (L1-bypass only). Once all blocks spin, nothing evicts the
//   stale cnt line -> wake-up happens via a cross-XCD eviction cascade
//   (~200us). Arrivals (RMW) were always coherent; only the POLL was stale.
// Fix: poll with SYSTEM-scope relaxed load (sc0+sc1 -> true bypass to the
//   coherence point; no invalidation, no RMW serialization). Everything else
//   is the round-3 verified code (absmax=0).
//
//   phase 1: block bx of batch b streams channels [4bx, 4bx+4) (64 KiB
//     contiguous, 1 KiB dense per wave-load). Lane row-parity (tid>>4)&1 is
//     invariant across iterations, so each lane keeps two sums (w-even/w-odd)
//     and the parity-split shuffle tree sorts them into the 4 polyphase
//     components. Partials published via relaxed agent-scope atomic stores
//     (write-through; consumers touch these lines first after the barrier ->
//     always fresh).
//   barrier: per-batch counter (32 lines, 64 arrivals each). Thread 0 does a
//     RELEASE agent fetch_add, then polls with SYSTEM-scope relaxed loads +
//     s_sleep backoff. Bounded spin guard -> fail loud, never hang.
//   phase 2: redundant deterministic argmax (strict > == jnp.argmax tie rule),
//     then gather of the winning component from this block's own 4 channels,
//     512 B/wave NT f2 stores.
//
// Grid (64,32) = 2048 blocks @ lb(256,8), ~20 VGPR -> exactly 8 blocks/CU on
// 256 CUs, fully co-resident (geometry accepted by round-2's cooperative
// launch; round-3's barrier completing correctly re-confirms it).

#define B 32
#define C 256
#define H 64
#define W 64
#define NBLK 64                               // blocks per batch
#define IN_F4_PER_BATCH (C * H * W / 4)       // 262144
#define F4_PER_BLK (IN_F4_PER_BATCH / NBLK)   // 4096 (= 4 channels = 64 KiB)
#define ITER1 (F4_PER_BLK / 256)              // 16
#define SEL_F2_PER_BATCH (C * 32 * 32 / 2)    // 131072 out float2 per batch
#define F2_PER_BLK (SEL_F2_PER_BATCH / NBLK)  // 2048
#define ITER2 (F2_PER_BLK / 256)              // 8
#define SPIN_GUARD (1 << 19)                  // ~0.1+ s worst case, then fail loud

typedef float floatx2 __attribute__((ext_vector_type(2)));

__global__ __launch_bounds__(256, 8) void aps_fused(const float4* __restrict__ x,
                                                    unsigned* __restrict__ cnt,
                                                    float* __restrict__ part,
                                                    floatx2* __restrict__ out) {
    const int b  = blockIdx.y;
    const int bx = blockIdx.x;
    const float4* xb = x + (size_t)b * IN_F4_PER_BATCH;
    const int lane = threadIdx.x & 63;
    const int wave = threadIdx.x >> 6;

    // ---- phase 1: partials over this block's 4 contiguous channels ----
    const int q0 = bx * F4_PER_BLK + threadIdx.x;
    float sA = 0.f, sB = 0.f;                 // w-even / w-odd sums
#pragma unroll 8
    for (int it = 0; it < ITER1; ++it) {
        float4 v = xb[q0 + it * 256];         // row parity (tid>>4)&1 invariant
        sA += v.x * v.x + v.z * v.z;
        sB += v.y * v.y + v.w * v.w;
    }
    // lanes 0-15,32-47 -> h even; 16-31,48-63 -> h odd
    sA += __shfl_down(sA, 32);  sB += __shfl_down(sB, 32);
#pragma unroll
    for (int off = 8; off; off >>= 1) {
        sA += __shfl_down(sA, off);  sB += __shfl_down(sB, off);
    }
    __shared__ float sm[4][4];   // [wave][comp]
    if (lane == 0)  { sm[wave][0] = sA; sm[wave][1] = sB; }
    if (lane == 16) { sm[wave][2] = sA; sm[wave][3] = sB; }
    __syncthreads();
    if (threadIdx.x < 4) {       // thread k publishes comp k's partial
        const int k = threadIdx.x;
        float t = sm[0][k] + sm[1][k] + sm[2][k] + sm[3][k];
        __hip_atomic_store(&part[(b * 4 + k) * NBLK + bx], t,
                           __ATOMIC_RELAXED, __HIP_MEMORY_SCOPE_AGENT);
    }
    __syncthreads();             // partial stores complete before release-add

    // ---- per-batch barrier: 64 arrivals on cnt[b] ----
    if (threadIdx.x == 0) {
        __hip_atomic_fetch_add(&cnt[b], 1u,
                               __ATOMIC_RELEASE, __HIP_MEMORY_SCOPE_AGENT);
        int guard = 0;
        // SYSTEM-scope poll: bypasses the (non-coherent, per-XCD) L2 so we
        // actually observe the last arrival instead of a stale cached count.
        while (__hip_atomic_load(&cnt[b], __ATOMIC_RELAXED,
                                 __HIP_MEMORY_SCOPE_SYSTEM) < NBLK &&
               guard < SPIN_GUARD) {
            __builtin_amdgcn_s_sleep(8);     // ~512 cyc backoff per poll
            ++guard;
        }
    }
    __syncthreads();             // fence for the whole block

    // ---- deterministic redundant argmax (same reduce order every block) ----
    float p = __hip_atomic_load(&part[(b * 4 + wave) * NBLK + lane],
                                __ATOMIC_RELAXED, __HIP_MEMORY_SCOPE_AGENT);
    for (int off = 32; off; off >>= 1) p += __shfl_down(p, off);
    __shared__ float s4[4];
    if (lane == 0) s4[wave] = p;
    __syncthreads();
    const float v0 = s4[0], v1 = s4[1], v2 = s4[2], v3 = s4[3];
    float best = v0;
    int k = 0;
    if (v1 > best) { best = v1; k = 1; }
    if (v2 > best) { best = v2; k = 2; }
    if (v3 > best) { k = 3; }
    const int di = k >> 1;       // h offset of winning component
    const int dj = k & 1;        // w offset

    // ---- gather from this block's own 4 channels (cache-warm) ----
    floatx2* ob = out + (size_t)b * SEL_F2_PER_BATCH;
    const int m0 = bx * F2_PER_BLK + threadIdx.x;
#pragma unroll
    for (int it = 0; it < ITER2; ++it) {
        const int m   = m0 + it * 256;
        const int ch  = m >> 9;          // 512 out f2 per channel
        const int r   = (m >> 4) & 31;   // output row
        const int col = m & 15;          // f4 column within input row
        float4 v = xb[(ch * 64 + 2 * r + di) * 16 + col];
        floatx2 o;
        if (dj == 0) { o.x = v.x; o.y = v.z; }   // w even
        else         { o.x = v.y; o.y = v.w; }   // w odd
        __builtin_nontemporal_store(o, ob + m);  // write-once -> NT
    }
}

extern "C" void kernel_launch(void* const* d_in, const int* in_sizes, int n_in,
                              void* d_out, int out_size, void* d_ws, size_t ws_size,
                              hipStream_t stream) {
    const float4* x = (const float4*)d_in[0];
    unsigned* cnt = (unsigned*)d_ws;          // 32 per-batch counters (128 B)
    float* part = (float*)d_ws + 64;          // 32*4*64 partials (32 KB), 256 B offset
    floatx2* out = (floatx2*)d_out;

    hipMemsetAsync(d_ws, 0, 128, stream);     // zero counters (ws is poisoned)
    aps_fused<<<dim3(NBLK, B), 256, 0, stream>>>(x, cnt, part, out);
}

// Round 5
// 329.282 us; speedup vs baseline: 2.3686x; 1.1757x over previous
//
#include <hip/hip_runtime.h>

// Input: x (32, 256, 64, 64) fp32. STRIDE=2, P=2. H,W even -> no padding.
//
// Single fused kernel with a hand-rolled per-batch barrier.
// Round-2 lesson: cg::grid.sync = ~580us (acquire-INVALIDATE per poll storm).
// Round-3/4 lesson: poll scope (agent vs system) is irrelevant (240 vs 245us).
//   The remaining shared suspect is the RELEASE agent fetch_add arrival: on
//   gfx950 an agent-release must conservatively buffer_wbl2 (write back the
//   per-XCD 4 MiB L2) so prior CACHED writes become visible. 2048 arrivals ->
//   ~256 wbL2 per XCD over an L2 full of streamed data ~= the observed 240us.
// Fix: the partials are published as RELAXED sc1 atomic stores (bypass L2,
//   complete at the Infinity-Cache coherence point) and __syncthreads already
//   drains vmcnt(0) -- so the arrival needs NO release. Demote to RELAXED.
//   Single-variable change vs the verified round-4 kernel (absmax=0).
//
//   phase 1: block bx of batch b streams channels [4bx, 4bx+4) (64 KiB
//     contiguous, 1 KiB dense per wave-load). Lane row-parity (tid>>4)&1 is
//     invariant across iterations, so each lane keeps two sums (w-even/w-odd)
//     and the parity-split shuffle tree sorts them into the 4 polyphase
//     components. Partials published via relaxed agent-scope atomic stores.
//   barrier: per-batch counter (32 lines, 64 arrivals each). Thread 0 does a
//     RELAXED agent fetch_add (stores already drained), then polls with
//     SYSTEM-scope relaxed loads + s_sleep backoff. Bounded spin guard ->
//     fail loud, never hang.
//   phase 2: redundant deterministic argmax (strict > == jnp.argmax tie rule)
//     over the 64 partials (relaxed sc1 atomic loads -> never stale), then
//     gather of the winning component from this block's own 4 channels,
//     512 B/wave NT f2 stores.
//
// Grid (64,32) = 2048 blocks @ lb(256,8), ~20 VGPR -> exactly 8 blocks/CU on
// 256 CUs, fully co-resident (barrier completion in rounds 3/4 confirms it).

#define B 32
#define C 256
#define H 64
#define W 64
#define NBLK 64                               // blocks per batch
#define IN_F4_PER_BATCH (C * H * W / 4)       // 262144
#define F4_PER_BLK (IN_F4_PER_BATCH / NBLK)   // 4096 (= 4 channels = 64 KiB)
#define ITER1 (F4_PER_BLK / 256)              // 16
#define SEL_F2_PER_BATCH (C * 32 * 32 / 2)    // 131072 out float2 per batch
#define F2_PER_BLK (SEL_F2_PER_BATCH / NBLK)  // 2048
#define ITER2 (F2_PER_BLK / 256)              // 8
#define SPIN_GUARD (1 << 19)                  // ~0.1+ s worst case, then fail loud

typedef float floatx2 __attribute__((ext_vector_type(2)));

__global__ __launch_bounds__(256, 8) void aps_fused(const float4* __restrict__ x,
                                                    unsigned* __restrict__ cnt,
                                                    float* __restrict__ part,
                                                    floatx2* __restrict__ out) {
    const int b  = blockIdx.y;
    const int bx = blockIdx.x;
    const float4* xb = x + (size_t)b * IN_F4_PER_BATCH;
    const int lane = threadIdx.x & 63;
    const int wave = threadIdx.x >> 6;

    // ---- phase 1: partials over this block's 4 contiguous channels ----
    const int q0 = bx * F4_PER_BLK + threadIdx.x;
    float sA = 0.f, sB = 0.f;                 // w-even / w-odd sums
#pragma unroll 8
    for (int it = 0; it < ITER1; ++it) {
        float4 v = xb[q0 + it * 256];         // row parity (tid>>4)&1 invariant
        sA += v.x * v.x + v.z * v.z;
        sB += v.y * v.y + v.w * v.w;
    }
    // lanes 0-15,32-47 -> h even; 16-31,48-63 -> h odd
    sA += __shfl_down(sA, 32);  sB += __shfl_down(sB, 32);
#pragma unroll
    for (int off = 8; off; off >>= 1) {
        sA += __shfl_down(sA, off);  sB += __shfl_down(sB, off);
    }
    __shared__ float sm[4][4];   // [wave][comp]
    if (lane == 0)  { sm[wave][0] = sA; sm[wave][1] = sB; }
    if (lane == 16) { sm[wave][2] = sA; sm[wave][3] = sB; }
    __syncthreads();
    if (threadIdx.x < 4) {       // thread k publishes comp k's partial
        const int k = threadIdx.x;
        float t = sm[0][k] + sm[1][k] + sm[2][k] + sm[3][k];
        // sc1 atomic store: bypasses the per-XCD L2, completes at the
        // Infinity-Cache coherence point -> consumers can never read stale.
        __hip_atomic_store(&part[(b * 4 + k) * NBLK + bx], t,
                           __ATOMIC_RELAXED, __HIP_MEMORY_SCOPE_AGENT);
    }
    __syncthreads();             // emits s_waitcnt vmcnt(0): partials drained

    // ---- per-batch barrier: 64 arrivals on cnt[b] ----
    if (threadIdx.x == 0) {
        // Partial stores are already at the coherence point (vmcnt drained by
        // __syncthreads). RELAXED arrival -> no agent-release buffer_wbl2
        // (the 2048x L2-writeback storm that cost ~240us in rounds 3/4).
        asm volatile("s_waitcnt vmcnt(0)" ::: "memory");   // free; already 0
        __hip_atomic_fetch_add(&cnt[b], 1u,
                               __ATOMIC_RELAXED, __HIP_MEMORY_SCOPE_AGENT);
        int guard = 0;
        while (__hip_atomic_load(&cnt[b], __ATOMIC_RELAXED,
                                 __HIP_MEMORY_SCOPE_SYSTEM) < NBLK &&
               guard < SPIN_GUARD) {
            __builtin_amdgcn_s_sleep(8);     // ~512 cyc backoff per poll
            ++guard;
        }
    }
    __syncthreads();             // fence for the whole block

    // ---- deterministic redundant argmax (same reduce order every block) ----
    float p = __hip_atomic_load(&part[(b * 4 + wave) * NBLK + lane],
                                __ATOMIC_RELAXED, __HIP_MEMORY_SCOPE_AGENT);
    for (int off = 32; off; off >>= 1) p += __shfl_down(p, off);
    __shared__ float s4[4];
    if (lane == 0) s4[wave] = p;
    __syncthreads();
    const float v0 = s4[0], v1 = s4[1], v2 = s4[2], v3 = s4[3];
    float best = v0;
    int k = 0;
    if (v1 > best) { best = v1; k = 1; }
    if (v2 > best) { best = v2; k = 2; }
    if (v3 > best) { k = 3; }
    const int di = k >> 1;       // h offset of winning component
    const int dj = k & 1;        // w offset

    // ---- gather from this block's own 4 channels (cache-warm) ----
    floatx2* ob = out + (size_t)b * SEL_F2_PER_BATCH;
    const int m0 = bx * F2_PER_BLK + threadIdx.x;
#pragma unroll
    for (int it = 0; it < ITER2; ++it) {
        const int m   = m0 + it * 256;
        const int ch  = m >> 9;          // 512 out f2 per channel
        const int r   = (m >> 4) & 31;   // output row
        const int col = m & 15;          // f4 column within input row
        float4 v = xb[(ch * 64 + 2 * r + di) * 16 + col];
        floatx2 o;
        if (dj == 0) { o.x = v.x; o.y = v.z; }   // w even
        else         { o.x = v.y; o.y = v.w; }   // w odd
        __builtin_nontemporal_store(o, ob + m);  // write-once -> NT
    }
}

extern "C" void kernel_launch(void* const* d_in, const int* in_sizes, int n_in,
                              void* d_out, int out_size, void* d_ws, size_t ws_size,
                              hipStream_t stream) {
    const float4* x = (const float4*)d_in[0];
    unsigned* cnt = (unsigned*)d_ws;          // 32 per-batch counters (128 B)
    float* part = (float*)d_ws + 64;          // 32*4*64 partials (32 KB), 256 B offset
    floatx2* out = (floatx2*)d_out;

    hipMemsetAsync(d_ws, 0, 128, stream);     // zero counters (ws is poisoned)
    aps_fused<<<dim3(NBLK, B), 256, 0, stream>>>(x, cnt, part, out);
}

// Round 6
// 208.521 us; speedup vs baseline: 3.7404x; 1.5791x over previous
//
#include <hip/hip_runtime.h>

// Input: x (32, 256, 64, 64) fp32. STRIDE=2, P=2. H,W even -> no padding.
//
// Two-kernel structure (reverted after rounds 2-5 proved every software
// grid barrier on gfx950 costs 150-580us across 2048 blocks; the kernel
// boundary costs ~4us). Bodies are the byte-verified round-5 fused phases
// split at the barrier, minus all atomics (kernel boundary = visibility).
//
// Pass 1 (aps_partials): block bx of batch b streams channels [4bx, 4bx+4)
//   (64 KiB contiguous, 1 KiB dense per wave-load). Lane row-parity
//   (tid>>4)&1 is invariant across the +256-f4 iteration stride, so each
//   lane keeps two sums (w-even / w-odd) and the parity-split shuffle tree
//   sorts them into the 4 polyphase components at reduction time.
//
// Pass 2 (aps_gather): same grid shape and same linear block id as pass 1
//   -> same XCD under the default id%8 assignment -> this block's 4 channels
//   may still sit in that XCD's L2 (and are guaranteed L3-hot). Redundant
//   per-block reduction of the 64 partials (strict > == jnp.argmax first-max
//   tie rule), then dense lane-contiguous f4 gather of the winning component
//   and 512 B/wave NT f2 stores (write-once; keeps x resident in caches).

#define B 32
#define C 256
#define H 64
#define W 64
#define NBLK 64                               // blocks per batch, both passes
#define IN_F4_PER_BATCH (C * H * W / 4)       // 262144
#define F4_PER_BLK (IN_F4_PER_BATCH / NBLK)   // 4096 (= 4 channels = 64 KiB)
#define ITER1 (F4_PER_BLK / 256)              // 16
#define SEL_F2_PER_BATCH (C * 32 * 32 / 2)    // 131072 out float2 per batch
#define F2_PER_BLK (SEL_F2_PER_BATCH / NBLK)  // 2048
#define ITER2 (F2_PER_BLK / 256)              // 8

typedef float floatx2 __attribute__((ext_vector_type(2)));

__global__ __launch_bounds__(256, 8) void aps_partials(const float4* __restrict__ x,
                                                       float* __restrict__ ws) {
    const int b  = blockIdx.y;
    const int bx = blockIdx.x;
    const float4* xb = x + (size_t)b * IN_F4_PER_BATCH;

    // ---- partials over this block's 4 contiguous channels ----
    const int q0 = bx * F4_PER_BLK + threadIdx.x;
    float sA = 0.f, sB = 0.f;                 // w-even / w-odd sums
#pragma unroll 8
    for (int it = 0; it < ITER1; ++it) {
        float4 v = xb[q0 + it * 256];         // row parity (tid>>4)&1 invariant
        sA += v.x * v.x + v.z * v.z;
        sB += v.y * v.y + v.w * v.w;
    }
    // lanes 0-15,32-47 -> h even; 16-31,48-63 -> h odd
    sA += __shfl_down(sA, 32);  sB += __shfl_down(sB, 32);
#pragma unroll
    for (int off = 8; off; off >>= 1) {
        sA += __shfl_down(sA, off);  sB += __shfl_down(sB, off);
    }
    // lane 0 holds (comp0, comp1); lane 16 holds (comp2, comp3)
    __shared__ float sm[4][4];   // [wave][comp]
    const int lane = threadIdx.x & 63;
    const int wave = threadIdx.x >> 6;
    if (lane == 0)  { sm[wave][0] = sA; sm[wave][1] = sB; }
    if (lane == 16) { sm[wave][2] = sA; sm[wave][3] = sB; }
    __syncthreads();
    if (threadIdx.x < 4) {       // thread k writes comp k's partial
        const int k = threadIdx.x;
        float t = sm[0][k] + sm[1][k] + sm[2][k] + sm[3][k];
        ws[(b * 4 + k) * NBLK + bx] = t;      // contiguous per (b,comp)
    }
}

__global__ __launch_bounds__(256, 8) void aps_gather(const float4* __restrict__ x,
                                                     const float* __restrict__ ws,
                                                     floatx2* __restrict__ out) {
    const int b  = blockIdx.y;
    const int bx = blockIdx.x;
    const int lane = threadIdx.x & 63;
    const int wave = threadIdx.x >> 6;   // 0..3 == component

    // ---- redundant deterministic argmax (L2/L3-hot 1 KiB per batch) ----
    float p = ws[(b * 4 + wave) * NBLK + lane];
    for (int off = 32; off; off >>= 1) p += __shfl_down(p, off);
    __shared__ float s4[4];
    if (lane == 0) s4[wave] = p;
    __syncthreads();
    const float v0 = s4[0], v1 = s4[1], v2 = s4[2], v3 = s4[3];
    float best = v0;
    int k = 0;
    if (v1 > best) { best = v1; k = 1; }
    if (v2 > best) { best = v2; k = 2; }
    if (v3 > best) { k = 3; }
    const int di = k >> 1;       // h offset of winning component
    const int dj = k & 1;        // w offset

    // ---- gather this block's own 4 channels (same XCD as pass-1 reader) ----
    const float4* xb = x + (size_t)b * IN_F4_PER_BATCH;
    floatx2* ob = out + (size_t)b * SEL_F2_PER_BATCH;
    const int m0 = bx * F2_PER_BLK + threadIdx.x;
#pragma unroll
    for (int it = 0; it < ITER2; ++it) {
        const int m   = m0 + it * 256;
        const int ch  = m >> 9;          // 512 out f2 per channel
        const int r   = (m >> 4) & 31;   // output row
        const int col = m & 15;          // f4 column within input row
        float4 v = xb[(ch * 64 + 2 * r + di) * 16 + col];
        floatx2 o;
        if (dj == 0) { o.x = v.x; o.y = v.z; }   // w even
        else         { o.x = v.y; o.y = v.w; }   // w odd
        __builtin_nontemporal_store(o, ob + m);  // write-once -> NT
    }
}

extern "C" void kernel_launch(void* const* d_in, const int* in_sizes, int n_in,
                              void* d_out, int out_size, void* d_ws, size_t ws_size,
                              hipStream_t stream) {
    const float4* x = (const float4*)d_in[0];
    float* ws = (float*)d_ws;             // 32*4*64 partials (32 KB)
    floatx2* out = (floatx2*)d_out;

    aps_partials<<<dim3(NBLK, B), 256, 0, stream>>>(x, ws);
    aps_gather<<<dim3(NBLK, B), 256, 0, stream>>>(x, ws, out);
}